// Round 1
// baseline (126.608 us; speedup 1.0000x reference)
//
#include <hip/hip_runtime.h>

// DCNv2 fused: deformable im2col + f16 MFMA GEMM.
// ws layout: [0, 8388608): xt = x transposed to (n, hw, C) as _Float16
//            [8388608, 9568256): wt = weight transposed to (o, k, c) as _Float16
// ws needed: ~9.6 MB.

typedef _Float16 f16x8 __attribute__((ext_vector_type(8)));
typedef float f32x4 __attribute__((ext_vector_type(4)));

#define C_IN 256
#define CO   256
#define KK   9
#define CK   2304   // C_IN * KK
#define HWSZ 4096   // 64*64

// ---- transpose x: (N,C,64,64) f32 -> xt[n][p][c] f16 ----
__global__ void transpose_x_kernel(const float* __restrict__ x,
                                   _Float16* __restrict__ xt) {
    __shared__ float tile[64][65];
    const int n  = blockIdx.z;
    const int p0 = blockIdx.x * 64;
    const int c0 = blockIdx.y * 64;
    const int tx = threadIdx.x & 63;
    const int ty = threadIdx.x >> 6;  // 0..3
    for (int i = 0; i < 16; ++i) {
        int c = ty * 16 + i;
        tile[c][tx] = x[((size_t)(n * C_IN + c0 + c) << 12) + p0 + tx];
    }
    __syncthreads();
    for (int i = 0; i < 16; ++i) {
        int p = ty * 16 + i;
        xt[((size_t)((n << 12) + p0 + p) << 8) + c0 + tx] = (_Float16)tile[tx][p];
    }
}

// ---- transpose weight: (Co, C, K) f32 -> wt[o][k][c] f16 ----
__global__ void transpose_w_kernel(const float* __restrict__ w,
                                   _Float16* __restrict__ wt) {
    const int o = blockIdx.x;
    const int c = threadIdx.x;
    for (int k = 0; k < KK; ++k)
        wt[o * CK + k * C_IN + c] = (_Float16)w[o * CK + c * KK + k];
}

// ---- fused main: block = 128 Co x 128 pixels, 8 waves ----
__launch_bounds__(512, 1)
__global__ void dcn_main_kernel(const float* __restrict__ offset,
                                const float* __restrict__ mask,
                                const float* __restrict__ bias,
                                const _Float16* __restrict__ xt,
                                const _Float16* __restrict__ wt,
                                float* __restrict__ out) {
    __shared__ ushort4 sidx[1152];          // 128 pix * 9 k : 4 clamped flat idx
    __shared__ float4  swgt[1152];          // 4 bilinear weights * mask * valid
    __shared__ _Float16 sB[128 * 40];       // [pix][ck-octet], stride 40 elems (80B)

    const int tid  = threadIdx.x;
    const int p0   = blockIdx.x * 128;      // global pixel base (includes n)
    const int m0   = blockIdx.y * 128;      // output-channel base
    const int n    = p0 >> 12;
    const int phw0 = p0 & 4095;

    // --- precompute bilinear params for 128 pixels x 9 kernel taps ---
    for (int t = tid; t < 1152; t += 512) {
        int pl = t / 9;
        int k  = t - pl * 9;
        int phw = phw0 + pl;
        int h = phw >> 6, w = phw & 63;
        float dy = offset[(size_t)(n * 18 + 2 * k)     * HWSZ + phw];
        float dx = offset[(size_t)(n * 18 + 2 * k + 1) * HWSZ + phw];
        float mv = mask  [(size_t)(n * 9 + k)          * HWSZ + phw];
        float py = dy + (float)(h - 1 + k / 3);
        float px = dx + (float)(w - 1 + k % 3);
        float y0f = floorf(py), x0f = floorf(px);
        int y0 = (int)y0f, x0 = (int)x0f;
        float wy1 = py - y0f, wx1 = px - x0f;
        float wy0 = 1.f - wy1, wx0 = 1.f - wx1;
        int y1 = y0 + 1, x1 = x0 + 1;
        float vy0 = (y0 >= 0 && y0 < 64) ? 1.f : 0.f;
        float vy1 = (y1 >= 0 && y1 < 64) ? 1.f : 0.f;
        float vx0 = (x0 >= 0 && x0 < 64) ? 1.f : 0.f;
        float vx1 = (x1 >= 0 && x1 < 64) ? 1.f : 0.f;
        int cy0 = min(max(y0, 0), 63), cy1 = min(max(y1, 0), 63);
        int cx0 = min(max(x0, 0), 63), cx1 = min(max(x1, 0), 63);
        sidx[t] = make_ushort4((unsigned short)(cy0 * 64 + cx0),
                               (unsigned short)(cy0 * 64 + cx1),
                               (unsigned short)(cy1 * 64 + cx0),
                               (unsigned short)(cy1 * 64 + cx1));
        swgt[t] = make_float4(wy0 * wx0 * mv * vy0 * vx0,
                              wy0 * wx1 * mv * vy0 * vx1,
                              wy1 * wx0 * mv * vy1 * vx0,
                              wy1 * wx1 * mv * vy1 * vx1);
    }
    __syncthreads();

    const int lane = tid & 63;
    const int wid  = tid >> 6;   // 0..7
    const int wm   = wid >> 2;   // 0..1  (64-row M slab)
    const int wn   = wid & 3;    // 0..3  (32-col N slab)
    const int l15  = lane & 15;
    const int lhi  = lane >> 4;  // 0..3

    f32x4 acc[4][2];
    for (int i = 0; i < 4; ++i)
        for (int j = 0; j < 2; ++j)
            acc[i][j] = (f32x4){0.f, 0.f, 0.f, 0.f};

    const int pixl = tid >> 2;   // staging: 0..127
    const int oct  = tid & 3;    // staging: c-octet 0..3
    const _Float16* xbase = xt + (((size_t)n) << 12) * C_IN;

    for (int s = 0; s < 72; ++s) {
        const int k  = s >> 3;
        const int c0 = (s & 7) * 32;
        // --- stage B tile: sampled[c0..c0+32)[pix] for kernel tap k ---
        {
            ushort4 idx = sidx[pixl * 9 + k];
            float4  w   = swgt[pixl * 9 + k];
            const int cb = c0 + oct * 8;
            f16x8 v0 = *(const f16x8*)(xbase + ((int)idx.x << 8) + cb);
            f16x8 v1 = *(const f16x8*)(xbase + ((int)idx.y << 8) + cb);
            f16x8 v2 = *(const f16x8*)(xbase + ((int)idx.z << 8) + cb);
            f16x8 v3 = *(const f16x8*)(xbase + ((int)idx.w << 8) + cb);
            f16x8 r;
            for (int e = 0; e < 8; ++e) {
                float f = w.x * (float)v0[e] + w.y * (float)v1[e]
                        + w.z * (float)v2[e] + w.w * (float)v3[e];
                r[e] = (_Float16)f;
            }
            *(f16x8*)(&sB[pixl * 40 + oct * 8]) = r;
        }
        __syncthreads();
        // --- fragments + MFMA ---
        f16x8 a[4], b[2];
        const int kf = k * 256 + c0 + lhi * 8;
        for (int fm = 0; fm < 4; ++fm) {
            int o = m0 + wm * 64 + fm * 16 + l15;
            a[fm] = *(const f16x8*)(wt + o * CK + kf);
        }
        for (int fn = 0; fn < 2; ++fn)
            b[fn] = *(const f16x8*)(&sB[(wn * 32 + fn * 16 + l15) * 40 + lhi * 8]);
        for (int fm = 0; fm < 4; ++fm)
            for (int fn = 0; fn < 2; ++fn)
                acc[fm][fn] = __builtin_amdgcn_mfma_f32_16x16x32_f16(
                    a[fm], b[fn], acc[fm][fn], 0, 0, 0);
        __syncthreads();
    }

    // --- epilogue: C/D layout col=lane&15 (pix), row=(lane>>4)*4+r (o) ---
    for (int fm = 0; fm < 4; ++fm) {
        for (int fn = 0; fn < 2; ++fn) {
            int pix = phw0 + wn * 32 + fn * 16 + l15;
            for (int r = 0; r < 4; ++r) {
                int o = m0 + wm * 64 + fm * 16 + lhi * 4 + r;
                out[((size_t)(n * CO + o) << 12) + pix] = acc[fm][fn][r] + bias[o];
            }
        }
    }
}

extern "C" void kernel_launch(void* const* d_in, const int* in_sizes, int n_in,
                              void* d_out, int out_size, void* d_ws, size_t ws_size,
                              hipStream_t stream) {
    const float* x      = (const float*)d_in[0];
    const float* offset = (const float*)d_in[1];
    const float* mask   = (const float*)d_in[2];
    const float* weight = (const float*)d_in[3];
    const float* bias   = (const float*)d_in[4];
    float* out = (float*)d_out;

    _Float16* xt = (_Float16*)d_ws;
    _Float16* wt = (_Float16*)((char*)d_ws + (size_t)4 * HWSZ * C_IN * 2);

    transpose_x_kernel<<<dim3(64, 4, 4), 256, 0, stream>>>(x, xt);
    transpose_w_kernel<<<CO, C_IN, 0, stream>>>(weight, wt);
    dcn_main_kernel<<<dim3(128, 2), 512, 0, stream>>>(offset, mask, bias, xt, wt, out);
}

// Round 2
// 103.380 us; speedup vs baseline: 1.2247x; 1.2247x over previous
//
#include <hip/hip_runtime.h>

// DCNv2 fused: deformable im2col + f16 MFMA GEMM, double-buffered + prefetched.
// ws: [0, 8388608)          xt = x transposed to (n, hw, C) f16
//     [8388608, 9568256)    wt = weight transposed to (o, k*c) f16

typedef _Float16 f16x8 __attribute__((ext_vector_type(8)));
typedef _Float16 f16x4 __attribute__((ext_vector_type(4)));
typedef float f32x4 __attribute__((ext_vector_type(4)));

#define C_IN 256
#define CO   256
#define KK   9
#define CK   2304
#define HWSZ 4096
#define NITER 72   // 9 taps * 8 c-chunks of 32

static __device__ __forceinline__ f16x8 splat8(_Float16 v) {
    f16x8 r = {v, v, v, v, v, v, v, v};
    return r;
}

// ---- transpose x: (N,C,64,64) f32 -> xt[n][p][c] f16 ----
__global__ void transpose_x_kernel(const float* __restrict__ x,
                                   _Float16* __restrict__ xt) {
    __shared__ float tile[64][65];
    const int n  = blockIdx.z;
    const int p0 = blockIdx.x * 64;
    const int c0 = blockIdx.y * 64;
    const int tx = threadIdx.x & 63;
    const int ty = threadIdx.x >> 6;  // 0..3
    for (int i = 0; i < 16; ++i) {
        int c = ty * 16 + i;
        tile[c][tx] = x[((size_t)(n * C_IN + c0 + c) << 12) + p0 + tx];
    }
    __syncthreads();
    for (int i = 0; i < 16; ++i) {
        int p = ty * 16 + i;
        xt[((size_t)((n << 12) + p0 + p) << 8) + c0 + tx] = (_Float16)tile[tx][p];
    }
}

// ---- transpose weight: (Co, C, K) f32 -> wt[o][k*256+c] f16 ----
__global__ void transpose_w_kernel(const float* __restrict__ w,
                                   _Float16* __restrict__ wt) {
    const int o = blockIdx.x;
    const int c = threadIdx.x;
    for (int k = 0; k < KK; ++k)
        wt[o * CK + k * C_IN + c] = (_Float16)w[o * CK + c * KK + k];
}

// ---- fused main: block = 128 Co x 64 pixels, 4 waves, 2 blocks/CU ----
__launch_bounds__(256, 2)
__global__ void dcn_main_kernel(const float* __restrict__ offset,
                                const float* __restrict__ mask,
                                const float* __restrict__ bias,
                                const _Float16* __restrict__ xt,
                                const _Float16* __restrict__ wt,
                                float* __restrict__ out) {
    __shared__ ushort4   sidx[576];        // 64 pix * 9 taps: 4 clamped flat idx
    __shared__ f16x4     swgt[576];        // 4 bilinear weights * mask * valid (f16)
    __shared__ _Float16  sB[2][64 * 40];   // double-buffered [pix][ck], stride 80B

    const int tid = threadIdx.x;
    // XCD-aware swizzle: each XCD gets 64 consecutive pixel-tiles (one n-slab).
    const int lin = blockIdx.x + 256 * blockIdx.y;      // 0..511
    const int swz = (lin & 7) * 64 + (lin >> 3);        // bijective (512 % 8 == 0)
    const int pt  = swz & 255;
    const int mt  = swz >> 8;
    const int p0   = pt * 64;
    const int m0   = mt * 128;
    const int n    = p0 >> 12;
    const int phw0 = p0 & 4095;

    // --- precompute bilinear params: 64 pixels x 9 taps ---
    for (int t = tid; t < 576; t += 256) {
        int pl = t / 9;
        int k  = t - pl * 9;
        int phw = phw0 + pl;
        int h = phw >> 6, w = phw & 63;
        float dy = offset[(size_t)(n * 18 + 2 * k)     * HWSZ + phw];
        float dx = offset[(size_t)(n * 18 + 2 * k + 1) * HWSZ + phw];
        float mv = mask  [(size_t)(n * 9 + k)          * HWSZ + phw];
        float py = dy + (float)(h - 1 + k / 3);
        float px = dx + (float)(w - 1 + k % 3);
        float y0f = floorf(py), x0f = floorf(px);
        int y0 = (int)y0f, x0 = (int)x0f;
        float wy1 = py - y0f, wx1 = px - x0f;
        float wy0 = 1.f - wy1, wx0 = 1.f - wx1;
        int y1 = y0 + 1, x1 = x0 + 1;
        float vy0 = (y0 >= 0 && y0 < 64) ? 1.f : 0.f;
        float vy1 = (y1 >= 0 && y1 < 64) ? 1.f : 0.f;
        float vx0 = (x0 >= 0 && x0 < 64) ? 1.f : 0.f;
        float vx1 = (x1 >= 0 && x1 < 64) ? 1.f : 0.f;
        int cy0 = min(max(y0, 0), 63), cy1 = min(max(y1, 0), 63);
        int cx0 = min(max(x0, 0), 63), cx1 = min(max(x1, 0), 63);
        sidx[t] = make_ushort4((unsigned short)(cy0 * 64 + cx0),
                               (unsigned short)(cy0 * 64 + cx1),
                               (unsigned short)(cy1 * 64 + cx0),
                               (unsigned short)(cy1 * 64 + cx1));
        f16x4 wv;
        wv.x = (_Float16)(wy0 * wx0 * mv * vy0 * vx0);
        wv.y = (_Float16)(wy0 * wx1 * mv * vy0 * vx1);
        wv.z = (_Float16)(wy1 * wx0 * mv * vy1 * vx0);
        wv.w = (_Float16)(wy1 * wx1 * mv * vy1 * vx1);
        swgt[t] = wv;
    }
    __syncthreads();

    const int lane = tid & 63;
    const int wid  = tid >> 6;   // 0..3
    const int wm   = wid >> 1;   // 0..1 (64-row M slab)
    const int wn   = wid & 1;    // 0..1 (32-col N slab)
    const int l15  = lane & 15;
    const int lhi  = lane >> 4;  // 0..3

    const int pixl = tid >> 2;   // staging pixel 0..63
    const int oct  = tid & 3;    // staging c-octet 0..3
    const _Float16* xb = xt + (((size_t)n) << 12) * C_IN;

    // A fragment base pointers: address is linear in tile index s (stride 32 f16)
    const _Float16* aptr[4];
    for (int fm = 0; fm < 4; ++fm)
        aptr[fm] = wt + (size_t)(m0 + wm * 64 + fm * 16 + l15) * CK + lhi * 8;

    f16x8 ga[2][4];   // gather corners, slot = tile & 1
    f16x8 aa[2][4];   // A fragments,   slot = tile & 1
    f32x4 acc[4][2];
    for (int i = 0; i < 4; ++i)
        for (int j = 0; j < 2; ++j)
            acc[i][j] = (f32x4){0.f, 0.f, 0.f, 0.f};

#define ISSUE_GATHER(T, SLOT)                                                 \
    {                                                                         \
        const int k_ = (T) >> 3;                                              \
        const int cb_ = (((T) & 7) << 5) + oct * 8;                           \
        ushort4 idx_ = sidx[pixl * 9 + k_];                                   \
        ga[SLOT][0] = *(const f16x8*)(xb + ((int)idx_.x << 8) + cb_);         \
        ga[SLOT][1] = *(const f16x8*)(xb + ((int)idx_.y << 8) + cb_);         \
        ga[SLOT][2] = *(const f16x8*)(xb + ((int)idx_.z << 8) + cb_);         \
        ga[SLOT][3] = *(const f16x8*)(xb + ((int)idx_.w << 8) + cb_);         \
    }

#define ISSUE_A(T, SLOT)                                                      \
    for (int fm_ = 0; fm_ < 4; ++fm_)                                         \
        aa[SLOT][fm_] = *(const f16x8*)(aptr[fm_] + (T) * 32);

#define COMBINE_STORE(T, SLOT)                                                \
    {                                                                         \
        const int k_ = (T) >> 3;                                              \
        f16x4 w_ = swgt[pixl * 9 + k_];                                       \
        f16x8 r_ = ga[SLOT][0] * splat8(w_.x) + ga[SLOT][1] * splat8(w_.y)    \
                 + ga[SLOT][2] * splat8(w_.z) + ga[SLOT][3] * splat8(w_.w);   \
        *(f16x8*)(&sB[SLOT][pixl * 40 + oct * 8]) = r_;                       \
    }

    // prologue: tile0 -> buf0 (combined now), tile1 loads in flight
    ISSUE_GATHER(0, 0)
    ISSUE_A(0, 0)
    ISSUE_GATHER(1, 1)
    ISSUE_A(1, 1)
    COMBINE_STORE(0, 0)
    __syncthreads();

    for (int su = 0; su < 36; ++su) {
#pragma unroll
        for (int half = 0; half < 2; ++half) {
            const int s = su * 2 + half;
            // MFMA on buffer `half` (tile s)
            f16x8 b[2];
            for (int fn = 0; fn < 2; ++fn)
                b[fn] = *(const f16x8*)(&sB[half][(wn * 32 + fn * 16 + l15) * 40 + lhi * 8]);
            for (int fm = 0; fm < 4; ++fm)
                for (int fn = 0; fn < 2; ++fn)
                    acc[fm][fn] = __builtin_amdgcn_mfma_f32_16x16x32_f16(
                        aa[half][fm], b[fn], acc[fm][fn], 0, 0, 0);
            if (s + 1 < NITER) {
                COMBINE_STORE(s + 1, half ^ 1)   // gathers issued one iter ago
            }
            if (s + 2 < NITER) {
                ISSUE_GATHER(s + 2, half)        // slot freed by last combine
                ISSUE_A(s + 2, half)             // regs freed by MFMA above
            }
            __syncthreads();
        }
    }

    // --- epilogue: C/D layout col=lane&15 (pix), row=(lane>>4)*4+r (o) ---
    for (int fm = 0; fm < 4; ++fm) {
        for (int fn = 0; fn < 2; ++fn) {
            int pix = phw0 + wn * 32 + fn * 16 + l15;
            for (int r = 0; r < 4; ++r) {
                int o = m0 + wm * 64 + fm * 16 + lhi * 4 + r;
                out[((size_t)(n * CO + o) << 12) + pix] = acc[fm][fn][r] + bias[o];
            }
        }
    }
#undef ISSUE_GATHER
#undef ISSUE_A
#undef COMBINE_STORE
}

extern "C" void kernel_launch(void* const* d_in, const int* in_sizes, int n_in,
                              void* d_out, int out_size, void* d_ws, size_t ws_size,
                              hipStream_t stream) {
    const float* x      = (const float*)d_in[0];
    const float* offset = (const float*)d_in[1];
    const float* mask   = (const float*)d_in[2];
    const float* weight = (const float*)d_in[3];
    const float* bias   = (const float*)d_in[4];
    float* out = (float*)d_out;

    _Float16* xt = (_Float16*)d_ws;
    _Float16* wt = (_Float16*)((char*)d_ws + (size_t)4 * HWSZ * C_IN * 2);

    transpose_x_kernel<<<dim3(64, 4, 4), 256, 0, stream>>>(x, xt);
    transpose_w_kernel<<<CO, C_IN, 0, stream>>>(weight, wt);
    dcn_main_kernel<<<dim3(256, 2), 256, 0, stream>>>(offset, mask, bias, xt, wt, out);
}

// Round 3
// 102.197 us; speedup vs baseline: 1.2389x; 1.0116x over previous
//
#include <hip/hip_runtime.h>

// DCNv2 fused: deformable im2col + f16 MFMA GEMM.
// R3: counted-wait barriers (no vmcnt(0) drain), triple-buffered LDS B,
//     K-step=64, taps-inner order for L1 gather reuse.
// ws: [0, 8388608)        xt = x transposed to (n, hw, C) f16
//     [8388608, 9568256)  wt = weight as [o][(cc*9+k)*32 + j] f16

typedef _Float16 f16x8 __attribute__((ext_vector_type(8)));
typedef _Float16 f16x4 __attribute__((ext_vector_type(4)));
typedef float f32x4 __attribute__((ext_vector_type(4)));

#define C_IN 256
#define CO   256
#define KK   9
#define CK   2304
#define HWSZ 4096
#define NSTEP 36       // K-steps of 64 (2 q-chunks of 32)
#define LDB  72        // sB row stride (elems), 64 used + 8 pad
#define BUFB (64 * LDB)

struct __align__(16) SP { ushort4 idx; f16x4 w; };

static __device__ __forceinline__ f16x8 splat8(_Float16 v) {
    f16x8 r = {v, v, v, v, v, v, v, v};
    return r;
}

// ---- transpose x: (N,C,64,64) f32 -> xt[n][p][c] f16 ----
__global__ void transpose_x_kernel(const float* __restrict__ x,
                                   _Float16* __restrict__ xt) {
    __shared__ float tile[64][65];
    const int n  = blockIdx.z;
    const int p0 = blockIdx.x * 64;
    const int c0 = blockIdx.y * 64;
    const int tx = threadIdx.x & 63;
    const int ty = threadIdx.x >> 6;
    for (int i = 0; i < 16; ++i) {
        int c = ty * 16 + i;
        tile[c][tx] = x[((size_t)(n * C_IN + c0 + c) << 12) + p0 + tx];
    }
    __syncthreads();
    for (int i = 0; i < 16; ++i) {
        int p = ty * 16 + i;
        xt[((size_t)((n << 12) + p0 + p) << 8) + c0 + tx] = (_Float16)tile[tx][p];
    }
}

// ---- weight: (Co,C,3,3) f32 -> wt[o][(cc*9+k)*32 + j] f16, c = cc*32+j ----
__global__ void transpose_w_kernel(const float* __restrict__ w,
                                   _Float16* __restrict__ wt) {
    const int o = blockIdx.x;
    const int c = threadIdx.x;
    for (int k = 0; k < KK; ++k)
        wt[o * CK + ((c >> 5) * 9 + k) * 32 + (c & 31)] =
            (_Float16)w[(o * C_IN + c) * KK + k];
}

// ---- fused main: block = 128 Co x 64 pixels, 4 waves, 2 blocks/CU ----
__launch_bounds__(256, 2)
__global__ void dcn_main_kernel(const float* __restrict__ offset,
                                const float* __restrict__ mask,
                                const float* __restrict__ bias,
                                const _Float16* __restrict__ xt,
                                const _Float16* __restrict__ wt,
                                float* __restrict__ out) {
    __shared__ SP sP[576];                 // [pix][tap]: corner idx + weights
    __shared__ _Float16 sB[3][BUFB];       // triple-buffered B tile [64pix][64ck]

    const int tid = threadIdx.x;
    const int lin = blockIdx.x + 256 * blockIdx.y;     // 0..511
    const int swz = (lin & 7) * 64 + (lin >> 3);       // XCD-contiguous
    const int pt  = swz & 255;
    const int mt  = swz >> 8;
    const int p0   = pt * 64;
    const int m0   = mt * 128;
    const int n    = p0 >> 12;
    const int phw0 = p0 & 4095;

    // --- precompute bilinear params: 64 pixels x 9 taps ---
    for (int t = tid; t < 576; t += 256) {
        int pl = t / 9;
        int k  = t - pl * 9;
        int phw = phw0 + pl;
        int h = phw >> 6, w = phw & 63;
        float dy = offset[(size_t)(n * 18 + 2 * k)     * HWSZ + phw];
        float dx = offset[(size_t)(n * 18 + 2 * k + 1) * HWSZ + phw];
        float mv = mask  [(size_t)(n * 9 + k)          * HWSZ + phw];
        float py = dy + (float)(h - 1 + k / 3);
        float px = dx + (float)(w - 1 + k % 3);
        float y0f = floorf(py), x0f = floorf(px);
        int y0 = (int)y0f, x0 = (int)x0f;
        float wy1 = py - y0f, wx1 = px - x0f;
        float wy0 = 1.f - wy1, wx0 = 1.f - wx1;
        int y1 = y0 + 1, x1 = x0 + 1;
        float vy0 = (y0 >= 0 && y0 < 64) ? 1.f : 0.f;
        float vy1 = (y1 >= 0 && y1 < 64) ? 1.f : 0.f;
        float vx0 = (x0 >= 0 && x0 < 64) ? 1.f : 0.f;
        float vx1 = (x1 >= 0 && x1 < 64) ? 1.f : 0.f;
        int cy0 = min(max(y0, 0), 63), cy1 = min(max(y1, 0), 63);
        int cx0 = min(max(x0, 0), 63), cx1 = min(max(x1, 0), 63);
        SP e;
        e.idx = make_ushort4((unsigned short)(cy0 * 64 + cx0),
                             (unsigned short)(cy0 * 64 + cx1),
                             (unsigned short)(cy1 * 64 + cx0),
                             (unsigned short)(cy1 * 64 + cx1));
        f16x4 wv;
        wv.x = (_Float16)(wy0 * wx0 * mv * vy0 * vx0);
        wv.y = (_Float16)(wy0 * wx1 * mv * vy0 * vx1);
        wv.z = (_Float16)(wy1 * wx0 * mv * vy1 * vx0);
        wv.w = (_Float16)(wy1 * wx1 * mv * vy1 * vx1);
        e.w = wv;
        sP[t] = e;
    }
    __syncthreads();

    const int lane = tid & 63;
    const int wid  = tid >> 6;   // 0..3
    const int wm   = wid >> 1;   // M slab (64 Co)
    const int wn   = wid & 1;    // N slab (32 pix)
    const int l15  = lane & 15;
    const int lhi  = lane >> 4;

    const int pixl  = tid >> 2;  // staging pixel 0..63
    const int oct   = tid & 3;   // staging c-octet
    const int pixl9 = pixl * 9;

    const char* xb  = (const char*)(xt + ((size_t)n << 12) * C_IN);
    const char* wtb = (const char*)wt;

    const int vBe = (wn * 32 + l15) * LDB + lhi * 8;   // B-read elem base
    const int vWe = pixl * LDB + oct * 8;              // B-write elem base

    unsigned voffA[4];
    for (int fm = 0; fm < 4; ++fm)
        voffA[fm] = (unsigned)(((m0 + wm * 64 + fm * 16 + l15) * CK + lhi * 8) * 2);

    unsigned aOffB = 0;              // byte offset of next-issued A k-slice
    unsigned chB_E = oct * 16;       // gather channel byte off (even q)
    unsigned chB_O = oct * 16;       // (odd q)
    int kiE = 0, kiO = 1;            // next-issued tap index (even/odd q)

    f16x8 ga[2][8];
    f16x8 aa[2][8];
    f16x4 gw[2][2];
    f32x4 acc[4][2];
    for (int i = 0; i < 4; ++i)
        for (int j = 0; j < 2; ++j)
            acc[i][j] = (f32x4){0.f, 0.f, 0.f, 0.f};

#define ISSUE_GA(SLOT)                                                        \
    {                                                                         \
        SP e0 = sP[pixl9 + kiE];                                              \
        SP e1 = sP[pixl9 + kiO];                                              \
        gw[SLOT][0] = e0.w;                                                   \
        gw[SLOT][1] = e1.w;                                                   \
        ga[SLOT][0] = *(const f16x8*)(xb + (((unsigned)e0.idx.x << 9) + chB_E)); \
        ga[SLOT][1] = *(const f16x8*)(xb + (((unsigned)e0.idx.y << 9) + chB_E)); \
        ga[SLOT][2] = *(const f16x8*)(xb + (((unsigned)e0.idx.z << 9) + chB_E)); \
        ga[SLOT][3] = *(const f16x8*)(xb + (((unsigned)e0.idx.w << 9) + chB_E)); \
        ga[SLOT][4] = *(const f16x8*)(xb + (((unsigned)e1.idx.x << 9) + chB_O)); \
        ga[SLOT][5] = *(const f16x8*)(xb + (((unsigned)e1.idx.y << 9) + chB_O)); \
        ga[SLOT][6] = *(const f16x8*)(xb + (((unsigned)e1.idx.z << 9) + chB_O)); \
        ga[SLOT][7] = *(const f16x8*)(xb + (((unsigned)e1.idx.w << 9) + chB_O)); \
        kiE += 2; if (kiE >= 9) { kiE -= 9; chB_E += 64; }                    \
        kiO += 2; if (kiO >= 9) { kiO -= 9; chB_O += 64; }                    \
    }

#define ISSUE_A(SLOT)                                                         \
    {                                                                         \
        for (int fm_ = 0; fm_ < 4; ++fm_) {                                   \
            unsigned vo_ = voffA[fm_] + aOffB;                                \
            aa[SLOT][fm_ * 2 + 0] = *(const f16x8*)(wtb + vo_);               \
            aa[SLOT][fm_ * 2 + 1] = *(const f16x8*)(wtb + vo_ + 64);          \
        }                                                                     \
        aOffB += 128;                                                         \
    }

#define COMBINE(SLOT, BUF)                                                    \
    {                                                                         \
        f16x4 w0_ = gw[SLOT][0], w1_ = gw[SLOT][1];                           \
        f16x8 r0_ = ga[SLOT][0] * splat8(w0_.x) + ga[SLOT][1] * splat8(w0_.y) \
                  + ga[SLOT][2] * splat8(w0_.z) + ga[SLOT][3] * splat8(w0_.w);\
        f16x8 r1_ = ga[SLOT][4] * splat8(w1_.x) + ga[SLOT][5] * splat8(w1_.y) \
                  + ga[SLOT][6] * splat8(w1_.z) + ga[SLOT][7] * splat8(w1_.w);\
        *(f16x8*)(&sB[BUF][vWe])      = r0_;                                  \
        *(f16x8*)(&sB[BUF][vWe + 32]) = r1_;                                  \
    }

#define MFMA_STEP(SLOT, BUF)                                                  \
    {                                                                         \
        f16x8 b00_ = *(const f16x8*)(&sB[BUF][vBe]);                          \
        f16x8 b01_ = *(const f16x8*)(&sB[BUF][vBe + 32]);                     \
        f16x8 b10_ = *(const f16x8*)(&sB[BUF][vBe + 16 * LDB]);               \
        f16x8 b11_ = *(const f16x8*)(&sB[BUF][vBe + 16 * LDB + 32]);          \
        for (int fm_ = 0; fm_ < 4; ++fm_) {                                   \
            acc[fm_][0] = __builtin_amdgcn_mfma_f32_16x16x32_f16(             \
                aa[SLOT][fm_ * 2 + 0], b00_, acc[fm_][0], 0, 0, 0);           \
            acc[fm_][0] = __builtin_amdgcn_mfma_f32_16x16x32_f16(             \
                aa[SLOT][fm_ * 2 + 1], b01_, acc[fm_][0], 0, 0, 0);           \
            acc[fm_][1] = __builtin_amdgcn_mfma_f32_16x16x32_f16(             \
                aa[SLOT][fm_ * 2 + 0], b10_, acc[fm_][1], 0, 0, 0);           \
            acc[fm_][1] = __builtin_amdgcn_mfma_f32_16x16x32_f16(             \
                aa[SLOT][fm_ * 2 + 1], b11_, acc[fm_][1], 0, 0, 0);           \
        }                                                                     \
    }

#define BAR()                                                                 \
    {                                                                         \
        asm volatile("s_waitcnt lgkmcnt(0)" ::: "memory");                    \
        __builtin_amdgcn_s_barrier();                                         \
        asm volatile("" ::: "memory");                                        \
    }

#define STEP(J, DO_GA, DO_A, DO_COMB, DO_BAR)                                 \
    {                                                                         \
        if (DO_GA) ISSUE_GA((J) & 1)                                          \
        MFMA_STEP((J) & 1, (J) % 3)                                           \
        if (DO_A)  ISSUE_A((J) & 1)                                           \
        if (DO_COMB) COMBINE(((J) + 1) & 1, ((J) + 1) % 3)                    \
        if (DO_BAR) BAR()                                                     \
    }

    // prologue: issue batches for steps 0 and 1, combine step 0 into buf 0
    ISSUE_GA(0)
    ISSUE_A(0)
    ISSUE_GA(1)
    ISSUE_A(1)
    COMBINE(0, 0)
    BAR()

    for (int rep = 0; rep < 5; ++rep) {     // steps 0..29
        STEP(0, 1, 1, 1, 1)
        STEP(1, 1, 1, 1, 1)
        STEP(2, 1, 1, 1, 1)
        STEP(3, 1, 1, 1, 1)
        STEP(4, 1, 1, 1, 1)
        STEP(5, 1, 1, 1, 1)
    }
    STEP(0, 1, 1, 1, 1)                     // s=30
    STEP(1, 1, 1, 1, 1)                     // s=31
    STEP(2, 1, 1, 1, 1)                     // s=32
    STEP(3, 1, 1, 1, 1)                     // s=33
    STEP(4, 0, 0, 1, 1)                     // s=34: no more issues
    STEP(5, 0, 0, 0, 0)                     // s=35: MFMA only

    // --- epilogue: C/D layout col=lane&15 (pix), row=(lane>>4)*4+r (o) ---
    for (int fm = 0; fm < 4; ++fm) {
        for (int fn = 0; fn < 2; ++fn) {
            int pix = phw0 + wn * 32 + fn * 16 + l15;
            for (int r = 0; r < 4; ++r) {
                int o = m0 + wm * 64 + fm * 16 + lhi * 4 + r;
                out[((size_t)(n * CO + o) << 12) + pix] = acc[fm][fn][r] + bias[o];
            }
        }
    }
#undef ISSUE_GA
#undef ISSUE_A
#undef COMBINE
#undef MFMA_STEP
#undef BAR
#undef STEP
}

extern "C" void kernel_launch(void* const* d_in, const int* in_sizes, int n_in,
                              void* d_out, int out_size, void* d_ws, size_t ws_size,
                              hipStream_t stream) {
    const float* x      = (const float*)d_in[0];
    const float* offset = (const float*)d_in[1];
    const float* mask   = (const float*)d_in[2];
    const float* weight = (const float*)d_in[3];
    const float* bias   = (const float*)d_in[4];
    float* out = (float*)d_out;

    _Float16* xt = (_Float16*)d_ws;
    _Float16* wt = (_Float16*)((char*)d_ws + (size_t)4 * HWSZ * C_IN * 2);

    transpose_x_kernel<<<dim3(64, 4, 4), 256, 0, stream>>>(x, xt);
    transpose_w_kernel<<<CO, C_IN, 0, stream>>>(weight, wt);
    dcn_main_kernel<<<dim3(256, 2), 256, 0, stream>>>(offset, mask, bias, xt, wt, out);
}